// Round 2
// baseline (192.017 us; speedup 1.0000x reference)
//
#include <hip/hip_runtime.h>

#define TPB 256

// ---------------------------------------------------------------------------
// partial_activation: Y[32] viewed as 16 blocks of 2, M=2, Q=2.0.
// pos[b] = #(Y[2b..2b+1] > 0); minI/maxI = FIRST argmin/argmax of pos;
// mask: *2 on max block if pos==2, *0 on min block if pos==0.
// train += relu-sum of min block (if min fails) + (-negsum) of max block (if max fails).
// succ += (min_succ && max_succ).
// All indexing is compile-time constant (cndmask chains) so Y stays in VGPRs
// (rule #20: runtime-indexed arrays spill to scratch).
// ---------------------------------------------------------------------------
__device__ __forceinline__ void partial_act(float (&Y)[32], float& t_acc, int& s_cnt)
{
    int pos[16];
#pragma unroll
    for (int b = 0; b < 16; ++b)
        pos[b] = (Y[2 * b] > 0.0f ? 1 : 0) + (Y[2 * b + 1] > 0.0f ? 1 : 0);

    int minv = pos[0], maxv = pos[0];
    int minI = 0, maxI = 0;
    float ymin0 = Y[0], ymin1 = Y[1];
    float ymax0 = Y[0], ymax1 = Y[1];
#pragma unroll
    for (int b = 1; b < 16; ++b) {
        bool lt = pos[b] < minv;   // strict < keeps FIRST argmin (matches jnp.argmin)
        minv  = lt ? pos[b]       : minv;
        minI  = lt ? b            : minI;
        ymin0 = lt ? Y[2 * b]     : ymin0;
        ymin1 = lt ? Y[2 * b + 1] : ymin1;
        bool gt = pos[b] > maxv;   // strict > keeps FIRST argmax (matches jnp.argmax)
        maxv  = gt ? pos[b]       : maxv;
        maxI  = gt ? b            : maxI;
        ymax0 = gt ? Y[2 * b]     : ymax0;
        ymax1 = gt ? Y[2 * b + 1] : ymax1;
    }
    bool min_succ = (minv == 0);
    bool max_succ = (maxv == 2);

    // train terms use PRE-mask Y values (reference reads Y before scaling).
    // y*(y>0) == max(y,0);  -y*(y<0) == -min(y,0)
    float cmin = fmaxf(ymin0, 0.0f) + fmaxf(ymin1, 0.0f);
    float cmax = -(fminf(ymax0, 0.0f) + fminf(ymax1, 0.0f));
    t_acc += (min_succ ? 0.0f : cmin) + (max_succ ? 0.0f : cmax);
    s_cnt += (min_succ && max_succ) ? 1 : 0;

    // apply mask (whole 2-element block since M == BLOCK == 2)
#pragma unroll
    for (int b = 0; b < 16; ++b) {
        bool ismax = max_succ && (b == maxI);
        bool ismin = min_succ && (b == minI);
        float mfac = ismax ? 2.0f : 1.0f;
        mfac = ismin ? 0.0f : mfac;
        Y[2 * b]     *= mfac;
        Y[2 * b + 1] *= mfac;
    }
}

// ---------------------------------------------------------------------------
// Main kernel: one thread per row. Weights are wave-uniform with constant
// offsets -> compiler emits s_load (scalar cache), amortized over 64 lanes.
// Scalar reductions finish in-kernel via threadfence + atomic last-block-done
// (saves a second serialized launch).
// ---------------------------------------------------------------------------
__global__ __launch_bounds__(TPB) void net_main(
    const float* __restrict__ x,
    const float* __restrict__ W1, const float* __restrict__ b1,
    const float* __restrict__ W2, const float* __restrict__ b2,
    const float* __restrict__ W3, const float* __restrict__ b3,
    float* __restrict__ out,
    float* __restrict__ t_part, int* __restrict__ c_part,
    unsigned* __restrict__ counter,
    int nrows, double inv_denom)
{
    const int row = blockIdx.x * TPB + threadIdx.x;

    float t_acc = 0.0f;
    int   s_cnt = 0;

    if (row < nrows) {
        const float2 xv = reinterpret_cast<const float2*>(x)[row];

        // ---- layer 1: Y = x @ W1^T + b1   (W1 is [32,2] row-major) ----
        float Y[32];
#pragma unroll
        for (int j = 0; j < 32; ++j)
            Y[j] = fmaf(xv.y, W1[2 * j + 1], fmaf(xv.x, W1[2 * j], b1[j]));

        partial_act(Y, t_acc, s_cnt);

        // ---- layer 2: Z = Y @ W2^T + b2   (W2 is [32,32] row-major) ----
        float Z[32];
#pragma unroll
        for (int j = 0; j < 32; ++j) {
            float acc = b2[j];
#pragma unroll
            for (int k = 0; k < 32; ++k)
                acc = fmaf(Y[k], W2[32 * j + k], acc);
            Z[j] = acc;
        }

        partial_act(Z, t_acc, s_cnt);

        // ---- layer 3 + softmax over 2 logits ----
        float z0 = b3[0], z1 = b3[1];
#pragma unroll
        for (int k = 0; k < 32; ++k) {
            z0 = fmaf(Z[k], W3[k], z0);
            z1 = fmaf(Z[k], W3[32 + k], z1);
        }
        float m  = fmaxf(z0, z1);
        float e0 = __expf(z0 - m);
        float e1 = __expf(z1 - m);
        float inv = 1.0f / (e0 + e1);
        float2 o;
        o.x = e0 * inv;
        o.y = e1 * inv;
        reinterpret_cast<float2*>(out)[row] = o;
    }

    // ---- block reduction: wave shuffle -> LDS -> per-block partial store ----
#pragma unroll
    for (int off = 32; off; off >>= 1) {
        t_acc += __shfl_down(t_acc, off);
        s_cnt += __shfl_down(s_cnt, off);
    }
    __shared__ float ts[TPB / 64];
    __shared__ int   cs[TPB / 64];
    __shared__ bool  amLast;
    const int wid  = threadIdx.x >> 6;
    const int lane = threadIdx.x & 63;
    if (lane == 0) { ts[wid] = t_acc; cs[wid] = s_cnt; }
    __syncthreads();
    if (threadIdx.x == 0) {
        float tt = ts[0];
        int   cc = cs[0];
#pragma unroll
        for (int w = 1; w < TPB / 64; ++w) { tt += ts[w]; cc += cs[w]; }
        t_part[blockIdx.x] = tt;
        c_part[blockIdx.x] = cc;
        __threadfence();                               // partials visible device-wide
        unsigned old = atomicAdd(counter, 1u);         // device-scope by default
        amLast = (old == gridDim.x - 1);
    }
    __syncthreads();

    // ---- last block reduces all partials (fixed order -> deterministic) ----
    if (amLast) {
        __threadfence();                               // acquire other blocks' stores
        double t = 0.0;
        int    c = 0;
        const int nparts = gridDim.x;
        for (int i = threadIdx.x; i < nparts; i += TPB) {
            t += (double)t_part[i];
            c += c_part[i];
        }
#pragma unroll
        for (int off = 32; off; off >>= 1) {
            t += __shfl_down(t, off);
            c += __shfl_down(c, off);
        }
        __shared__ double td[TPB / 64];
        __shared__ int    cd[TPB / 64];
        if (lane == 0) { td[wid] = t; cd[wid] = c; }
        __syncthreads();
        if (threadIdx.x == 0) {
            double tt = 0.0;
            int    cc = 0;
#pragma unroll
            for (int w = 0; w < TPB / 64; ++w) { tt += td[w]; cc += cd[w]; }
            float* scal = out + (size_t)nrows * 2;
            scal[0] = (float)((double)cc * inv_denom); // succ = cnt / (2B)
            scal[1] = (float)tt;                       // train = t1 + t2
        }
    }
}

extern "C" void kernel_launch(void* const* d_in, const int* in_sizes, int n_in,
                              void* d_out, int out_size, void* d_ws, size_t ws_size,
                              hipStream_t stream)
{
    const float* x  = (const float*)d_in[0];
    const float* W1 = (const float*)d_in[1];
    const float* b1 = (const float*)d_in[2];
    const float* W2 = (const float*)d_in[3];
    const float* b2 = (const float*)d_in[4];
    const float* W3 = (const float*)d_in[5];
    const float* b3 = (const float*)d_in[6];
    float* out = (float*)d_out;

    const int nrows   = in_sizes[0] / 2;          // B = 1048576
    const int nblocks = (nrows + TPB - 1) / TPB;  // 4096

    float*    t_part  = (float*)d_ws;
    int*      c_part  = (int*)((char*)d_ws + (size_t)nblocks * sizeof(float));
    unsigned* counter = (unsigned*)((char*)d_ws + (size_t)nblocks * 2 * sizeof(float));

    // ws is poisoned 0xAA before every timed launch -> zero the done-counter.
    // hipMemsetAsync on the capture stream is graph-capture legal.
    hipMemsetAsync(counter, 0, sizeof(unsigned), stream);

    net_main<<<nblocks, TPB, 0, stream>>>(x, W1, b1, W2, b2, W3, b3,
                                          out, t_part, c_part, counter,
                                          nrows, 1.0 / (2.0 * (double)nrows));
}